// Round 1
// baseline (133.649 us; speedup 1.0000x reference)
//
#include <hip/hip_runtime.h>
#include <hip/hip_bf16.h>
#include <cstddef>

#define BB 4
#define CC 64
#define UU 5
#define VV 5
#define HH 64
#define WW 64
#define NIJ (69*69)   // 4761

__device__ __forceinline__ float rdlane(float v, int l) {
    return __uint_as_float((unsigned)__builtin_amdgcn_readlane((int)__float_as_uint(v), l));
}

// ---------------------------------------------------------------------------
// K1: one pass over x -> 4 means, assembled channel-last into grid_t[b][ij][c]
// grid: B*C = 256 blocks, 512 threads
// ---------------------------------------------------------------------------
__global__ __launch_bounds__(512) void k1_means(const float* __restrict__ x,
                                                float* __restrict__ grid_t) {
    const int bc = blockIdx.x;            // b*64 + c
    const int b  = bc >> 6;
    const int c  = bc & 63;
    const float* xb = x + (size_t)bc * (UU*VV*HH*WW);   // 25*4096

    const int t    = threadIdx.x;         // 0..511
    const int wave = t >> 6;
    const int lane = t & 63;

    __shared__ float  uh_lds[UU*HH];      // 320: sum over (v,w), per (u,h)
    __shared__ float4 vw_lds4[VV*16];     // 5 rows of 64 (as 16 float4): sum over (u,h)
    __shared__ float4 vw_part[8*16];      // per-wave partials for one tile
    __shared__ float  uv_lds[UU*VV];      // 25: per-tile totals

    for (int idx = t; idx < UU*HH; idx += 512) uh_lds[idx] = 0.f;
    for (int idx = t; idx < VV*16*4; idx += 512) ((float*)vw_lds4)[idx] = 0.f;
    __syncthreads();

    // register accumulator for hw-mean: thread owns float4 f = 512k + t, k=0,1
    float4 hwacc[2];
    hwacc[0] = make_float4(0.f,0.f,0.f,0.f);
    hwacc[1] = make_float4(0.f,0.f,0.f,0.f);

    for (int u = 0; u < UU; ++u) {
        for (int vv = 0; vv < VV; ++vv) {
            const float4* xt = (const float4*)(xb + (size_t)(u*VV + vv) * (HH*WW));
            float4 cs = make_float4(0.f,0.f,0.f,0.f);
            #pragma unroll
            for (int k = 0; k < 2; ++k) {
                const int f = (k << 9) + t;        // 0..1023
                float4 xv = xt[f];
                hwacc[k].x += xv.x; hwacc[k].y += xv.y;
                hwacc[k].z += xv.z; hwacc[k].w += xv.w;
                cs.x += xv.x; cs.y += xv.y; cs.z += xv.z; cs.w += xv.w;
                // row sum over w: 16 lanes (same l>>4 group) cover one h-row
                float rs = (xv.x + xv.y) + (xv.z + xv.w);
                rs += __shfl_xor(rs, 1);
                rs += __shfl_xor(rs, 2);
                rs += __shfl_xor(rs, 4);
                rs += __shfl_xor(rs, 8);
                if ((t & 15) == 0) {
                    const int h = (k << 5) + (t >> 4);
                    uh_lds[u*HH + h] += rs;        // race-free: unique h per thread/k
                }
            }
            // column partials: reduce cs across the 4 sub-rows of this wave
            cs.x += __shfl_xor(cs.x, 16); cs.y += __shfl_xor(cs.y, 16);
            cs.z += __shfl_xor(cs.z, 16); cs.w += __shfl_xor(cs.w, 16);
            cs.x += __shfl_xor(cs.x, 32); cs.y += __shfl_xor(cs.y, 32);
            cs.z += __shfl_xor(cs.z, 32); cs.w += __shfl_xor(cs.w, 32);
            if (lane < 16) vw_part[wave*16 + lane] = cs;
            __syncthreads();
            if (t < 16) {
                float4 s4 = make_float4(0.f,0.f,0.f,0.f);
                #pragma unroll
                for (int w8 = 0; w8 < 8; ++w8) {
                    float4 p = vw_part[w8*16 + t];
                    s4.x += p.x; s4.y += p.y; s4.z += p.z; s4.w += p.w;
                }
                float4 acc = vw_lds4[vv*16 + t];
                acc.x += s4.x; acc.y += s4.y; acc.z += s4.z; acc.w += s4.w;
                vw_lds4[vv*16 + t] = acc;
                float s = (s4.x + s4.y) + (s4.z + s4.w);
                s += __shfl_xor(s, 1);
                s += __shfl_xor(s, 2);
                s += __shfl_xor(s, 4);
                s += __shfl_xor(s, 8);
                if (t == 0) uv_lds[u*VV + vv] = s;
            }
            __syncthreads();
        }
    }

    // ---- write out to grid_t, channel-last: grid_t[(b*NIJ + ij)*64 + c]
    float* gtb = grid_t + (size_t)b * NIJ * CC + c;
    // hw region: ij = h*69 + w, scale 1/25
    #pragma unroll
    for (int k = 0; k < 2; ++k) {
        const int f  = (k << 9) + t;
        const int h  = f >> 4;
        const int w0 = (f & 15) << 2;
        const float sc = 1.f / 25.f;
        gtb[(size_t)(h*69 + w0 + 0) * CC] = hwacc[k].x * sc;
        gtb[(size_t)(h*69 + w0 + 1) * CC] = hwacc[k].y * sc;
        gtb[(size_t)(h*69 + w0 + 2) * CC] = hwacc[k].z * sc;
        gtb[(size_t)(h*69 + w0 + 3) * CC] = hwacc[k].w * sc;
    }
    if (t < UU*HH) {   // uh: ij = h*69 + 64 + u, scale 1/320
        const int u = t >> 6, h = t & 63;
        gtb[(size_t)(h*69 + 64 + u) * CC] = uh_lds[t] * (1.f/320.f);
    }
    if (t < VV*WW) {   // vw: ij = (64+v)*69 + w, scale 1/320
        const int vv = t >> 6, w = t & 63;
        gtb[(size_t)((64+vv)*69 + w) * CC] = ((float*)vw_lds4)[vv*64 + w] * (1.f/320.f);
    }
    if (t < UU*VV) {   // uv: ij = (64+v)*69 + 64 + u, scale 1/4096
        const int u = t / 5, vv = t % 5;
        gtb[(size_t)((64+vv)*69 + 64 + u) * CC] = uv_lds[t] * (1.f/4096.f);
    }
}

// ---------------------------------------------------------------------------
// K2: per-position MLP (w1/silu/w2) + region conv (fw0..3), lane = out channel
// grid: B*69 = 276 blocks (one grid row each), 256 threads = 4 waves
// ---------------------------------------------------------------------------
#define LOADROW(dst, src)                                              \
    { _Pragma("unroll")                                                \
      for (int q = 0; q < 16; ++q) {                                   \
          float4 t4 = ((const float4*)(src))[lane*16 + q];             \
          dst[4*q+0] = t4.x; dst[4*q+1] = t4.y;                        \
          dst[4*q+2] = t4.z; dst[4*q+3] = t4.w;                        \
      } }

#define DOT64(res, wr, src)                                            \
    float res;                                                         \
    { float _a0=0.f,_a1=0.f,_a2=0.f,_a3=0.f;                           \
      _Pragma("unroll")                                                \
      for (int cc2 = 0; cc2 < 64; cc2 += 4) {                          \
          _a0 = fmaf(wr[cc2+0], rdlane(src, cc2+0), _a0);              \
          _a1 = fmaf(wr[cc2+1], rdlane(src, cc2+1), _a1);              \
          _a2 = fmaf(wr[cc2+2], rdlane(src, cc2+2), _a2);              \
          _a3 = fmaf(wr[cc2+3], rdlane(src, cc2+3), _a3);              \
      }                                                                \
      res = (_a0 + _a1) + (_a2 + _a3); }

#define MLP_BODY(J)                                                    \
    {                                                                  \
        const int jj = (J);                                            \
        float v = gtb[(size_t)(i*69 + jj) * CC + lane];                \
        DOT64(d1, w1r, v);                                             \
        float acc1 = d1 + b1v;                                         \
        float ya = acc1 / (1.f + __expf(-acc1));                       \
        DOT64(d2, w2r, ya);                                            \
        float acc2 = d2 + b2v;                                         \
        DOT64(d3, fr, acc2);                                           \
        sp[(size_t)(jj - jbase) * sstr] = d3 + fbv;                    \
    }

__global__ __launch_bounds__(256) void k2_mlp(
        const float* __restrict__ grid_t,
        const float* __restrict__ w1, const float* __restrict__ b1,
        const float* __restrict__ w2, const float* __restrict__ b2,
        const float* __restrict__ fw0, const float* __restrict__ fb0,
        const float* __restrict__ fw1, const float* __restrict__ fb1,
        const float* __restrict__ fw2, const float* __restrict__ fb2,
        const float* __restrict__ fw3, const float* __restrict__ fb3,
        float* __restrict__ mod_hw, float* __restrict__ mod_uh,
        float* __restrict__ mod_vw, float* __restrict__ mod_uv) {
    const int row  = blockIdx.x;          // 0..275
    const int b    = row / 69;
    const int i    = row % 69;
    const int wave = threadIdx.x >> 6;
    const int lane = threadIdx.x & 63;

    const int j0 = wave * 18;
    const int j1 = min(69, j0 + 18);
    const bool top = (i < 64);

    const float* fwA = top ? fw0 : fw3;
    const float* fbA = top ? fb0 : fb3;
    const float* fwB = top ? fw2 : fw1;
    const float* fbB = top ? fb2 : fb1;

    float w1r[64], w2r[64], fr[64];
    LOADROW(w1r, w1);
    LOADROW(w2r, w2);
    const float b1v = b1[lane];
    const float b2v = b2[lane];

    const float* gtb = grid_t + (size_t)b * NIJ * CC;
    const int cbl = b * CC + lane;        // output channel index with batch

    const int jm = min(j1, 64);
    if (j0 < jm) {                        // region A: j < 64
        LOADROW(fr, fwA);
        const float fbv = fbA[lane];
        float* sp; int sstr; const int jbase = 0;
        if (top) { sp = mod_hw + ((size_t)cbl*64 + i)*64;          sstr = 1; }  // [c][h=i][w=j]
        else     { sp = mod_vw + (size_t)cbl*320 + (i-64)*64;      sstr = 1; }  // [c][v=i-64][w=j]
        for (int j = j0; j < jm; ++j) MLP_BODY(j)
    }
    if (j1 > 64) {                        // region B: j >= 64
        LOADROW(fr, fwB);
        const float fbv = fbB[lane];
        float* sp; int sstr; const int jbase = 64;
        if (top) { sp = mod_uh + (size_t)cbl*320 + i;              sstr = 64; } // [c][u=j-64][h=i]
        else     { sp = mod_uv + (size_t)cbl*25 + (i-64);          sstr = 5;  } // [c][u=j-64][v=i-64]
        const int jb = max(j0, 64);
        for (int j = jb; j < j1; ++j) MLP_BODY(j)
    }
}

// ---------------------------------------------------------------------------
// K3: out = x * (mod_hw + mod_uv + mod_uh + mod_vw)
// grid: B*C*U*V = 1600 blocks, 512 threads, float4 streaming
// ---------------------------------------------------------------------------
__global__ __launch_bounds__(512) void k3_apply(
        const float* __restrict__ x,
        const float* __restrict__ mod_hw, const float* __restrict__ mod_uh,
        const float* __restrict__ mod_vw, const float* __restrict__ mod_uv,
        float* __restrict__ out) {
    const int blk = blockIdx.x;           // (b*C + c)*25 + u*5 + v
    const int vv  = blk % 5;
    const int u   = (blk / 5) % 5;
    const int bc  = blk / 25;

    const size_t xoff = ((size_t)bc * 25 + u*5 + vv) * (HH*WW);
    const float4* x4 = (const float4*)(x + xoff);
    float4* o4 = (float4*)(out + xoff);
    const float4* mhw4 = (const float4*)(mod_hw + (size_t)bc * (HH*WW));

    __shared__ float  uh_s[HH];
    __shared__ float4 vw_s4[16];

    const int t = threadIdx.x;
    if (t < 64) uh_s[t] = mod_uh[(size_t)bc*320 + u*64 + t];
    else if (t < 128) {
        const int w = t - 64;
        ((float*)vw_s4)[w] = mod_vw[(size_t)bc*320 + vv*64 + w];
    }
    const float muv = mod_uv[(size_t)bc*25 + u*5 + vv];
    __syncthreads();

    #pragma unroll
    for (int k = 0; k < 2; ++k) {
        const int f = (k << 9) + t;       // 0..1023
        const int h = f >> 4;
        float4 xv = x4[f];
        float4 mh = mhw4[f];
        float4 vw = vw_s4[f & 15];
        const float s = muv + uh_s[h];
        float4 r;
        r.x = xv.x * (mh.x + vw.x + s);
        r.y = xv.y * (mh.y + vw.y + s);
        r.z = xv.z * (mh.z + vw.z + s);
        r.w = xv.w * (mh.w + vw.w + s);
        o4[f] = r;
    }
}

// ---------------------------------------------------------------------------
extern "C" void kernel_launch(void* const* d_in, const int* in_sizes, int n_in,
                              void* d_out, int out_size, void* d_ws, size_t ws_size,
                              hipStream_t stream) {
    const float* x   = (const float*)d_in[0];
    const float* w1  = (const float*)d_in[1];
    const float* b1  = (const float*)d_in[2];
    const float* w2  = (const float*)d_in[3];
    const float* b2  = (const float*)d_in[4];
    const float* fw0 = (const float*)d_in[5];
    const float* fb0 = (const float*)d_in[6];
    const float* fw1 = (const float*)d_in[7];
    const float* fb1 = (const float*)d_in[8];
    const float* fw2 = (const float*)d_in[9];
    const float* fb2 = (const float*)d_in[10];
    const float* fw3 = (const float*)d_in[11];
    const float* fb3 = (const float*)d_in[12];

    float* ws = (float*)d_ws;
    float* grid_t = ws;                       // B*NIJ*C           = 1,218,816
    float* mod_hw = ws + 1218816;             // B*C*64*64         = 1,048,576
    float* mod_uh = ws + 1218816 + 1048576;   // B*C*5*64          = 81,920
    float* mod_vw = ws + 1218816 + 1048576 + 81920;
    float* mod_uv = ws + 1218816 + 1048576 + 81920 + 81920;   // B*C*25 = 6,400

    k1_means<<<BB*CC, 512, 0, stream>>>(x, grid_t);
    k2_mlp<<<BB*69, 256, 0, stream>>>(grid_t, w1, b1, w2, b2,
                                      fw0, fb0, fw1, fb1, fw2, fb2, fw3, fb3,
                                      mod_hw, mod_uh, mod_vw, mod_uv);
    k3_apply<<<BB*CC*UU*VV, 512, 0, stream>>>(x, mod_hw, mod_uh, mod_vw, mod_uv,
                                              (float*)d_out);
}